// Round 2
// baseline (455.802 us; speedup 1.0000x reference)
//
#include <hip/hip_runtime.h>

// ---------- helpers ----------
static __device__ __forceinline__ void fma4(float4& a, float s, float4 v) {
  a.x = fmaf(s, v.x, a.x);
  a.y = fmaf(s, v.y, a.y);
  a.z = fmaf(s, v.z, a.z);
  a.w = fmaf(s, v.w, a.w);
}
static __device__ __forceinline__ float4 relu4(float4 a) {
  return make_float4(fmaxf(a.x, 0.f), fmaxf(a.y, 0.f),
                     fmaxf(a.z, 0.f), fmaxf(a.w, 0.f));
}

// ---------- transpose x (16,C,H,W) -> xt [C][H][W][16] ----------
__global__ void k_transpose(const float* __restrict__ x, float* __restrict__ xt,
                            int chw, int total) {
  int p = blockIdx.x * blockDim.x + threadIdx.x;
  if (p >= total) return;
  float v[16];
#pragma unroll
  for (int b = 0; b < 16; ++b) v[b] = x[(size_t)b * chw + p];
  float4* o4 = reinterpret_cast<float4*>(xt) + (size_t)p * 4;
#pragma unroll
  for (int q = 0; q < 4; ++q)
    o4[q] = make_float4(v[4 * q + 0], v[4 * q + 1], v[4 * q + 2], v[4 * q + 3]);
}

// ---------- locally-connected conv, 16 batch per thread ----------
// xt  : [C][IH][IW][16], wgt: [O][C][OH][OW][36], bias: [O][OH][OW]
// out : [O][OH][OW][16];  thread per (o,h,w)
template <int C, int IH, int IW, int OH, int OW, int S>
__global__ void k_lc16(const float* __restrict__ xt, const float* __restrict__ wgt,
                       const float* __restrict__ bias, float* __restrict__ out,
                       int total) {
  int p = blockIdx.x * blockDim.x + threadIdx.x;
  if (p >= total) return;
  int w = p % OW;
  int r = p / OW;
  int h = r % OH;
  int o = r / OH;

  float bv = bias[(o * OH + h) * OW + w];
  float4 a0 = make_float4(bv, bv, bv, bv), a1 = a0, a2 = a0, a3 = a0;

  const float4* x4 = reinterpret_cast<const float4*>(xt);
  for (int c = 0; c < C; ++c) {
    const float4* wp = reinterpret_cast<const float4*>(wgt) +
                       ((size_t)((o * C + c) * OH + h) * OW + w) * 9;
    const float4* xc = x4 + ((size_t)(c * IH + h * S) * IW + w * S) * 4;
#pragma unroll
    for (int k4 = 0; k4 < 9; ++k4) {
      float4 wv = wp[k4];
#pragma unroll
      for (int rr = 0; rr < 4; ++rr) {
        int k = k4 * 4 + rr;
        int ki = k / 6, kj = k % 6;
        const float4* xp = xc + ((size_t)(ki * IW + kj)) * 4;
        float s = rr == 0 ? wv.x : rr == 1 ? wv.y : rr == 2 ? wv.z : wv.w;
        fma4(a0, s, xp[0]);
        fma4(a1, s, xp[1]);
        fma4(a2, s, xp[2]);
        fma4(a3, s, xp[3]);
      }
    }
  }
  float4* op = reinterpret_cast<float4*>(out) + (size_t)p * 4;
  op[0] = relu4(a0);
  op[1] = relu4(a1);
  op[2] = relu4(a2);
  op[3] = relu4(a3);
}

// ---------- locally-connected conv, 4 batch per thread (for small layers) ----
template <int C, int IH, int IW, int OH, int OW, int S>
__global__ void k_lc(const float* __restrict__ xt, const float* __restrict__ wgt,
                     const float* __restrict__ bias, float* __restrict__ out,
                     int total) {
  int t = blockIdx.x * blockDim.x + threadIdx.x;
  if (t >= total) return;
  int bq = t & 3;
  int p = t >> 2;
  int w = p % OW; p /= OW;
  int h = p % OH; p /= OH;
  int o = p;

  float bv = bias[(o * OH + h) * OW + w];
  float4 acc = make_float4(bv, bv, bv, bv);

  const float4* x4 = reinterpret_cast<const float4*>(xt);
  for (int c = 0; c < C; ++c) {
    const float4* wp = reinterpret_cast<const float4*>(wgt) +
                       ((size_t)((o * C + c) * OH + h) * OW + w) * 9;
    const float4* xc = x4 + ((size_t)(c * IH + h * S) * IW + w * S) * 4 + bq;
#pragma unroll
    for (int k4 = 0; k4 < 9; ++k4) {
      float4 wv = wp[k4];
#pragma unroll
      for (int rr = 0; rr < 4; ++rr) {
        int k = k4 * 4 + rr;
        int i = k / 6, j = k % 6;
        float4 xv = xc[(i * IW + j) * 4];
        float s = rr == 0 ? wv.x : rr == 1 ? wv.y : rr == 2 ? wv.z : wv.w;
        fma4(acc, s, xv);
      }
    }
  }
  reinterpret_cast<float4*>(out)[((size_t)(o * OH + h) * OW + w) * 4 + bq] =
      relu4(acc);
}

// ---------- 2x2 maxpool on [O][IH][IW][16] -> [O][PH][PW][16] ----------
__global__ void k_pool(const float* __restrict__ in, float* __restrict__ out,
                       int IH, int IW, int PH, int PW, int total) {
  int t = blockIdx.x * blockDim.x + threadIdx.x;
  if (t >= total) return;
  int bq = t & 3;
  int p = t >> 2;
  int w = p % PW; p /= PW;
  int h = p % PH; p /= PH;
  int o = p;
  const float4* in4 = reinterpret_cast<const float4*>(in);
  size_t r0 = ((size_t)(o * IH + 2 * h) * IW + 2 * w) * 4 + bq;
  float4 a = in4[r0];
  float4 b = in4[r0 + 4];
  float4 c = in4[r0 + (size_t)IW * 4];
  float4 d = in4[r0 + (size_t)IW * 4 + 4];
  float4 m;
  m.x = fmaxf(fmaxf(a.x, b.x), fmaxf(c.x, d.x));
  m.y = fmaxf(fmaxf(a.y, b.y), fmaxf(c.y, d.y));
  m.z = fmaxf(fmaxf(a.z, b.z), fmaxf(c.z, d.z));
  m.w = fmaxf(fmaxf(a.w, b.w), fmaxf(c.w, d.w));
  reinterpret_cast<float4*>(out)[((size_t)(o * PH + h) * PW + w) * 4 + bq] = m;
}

// ---------- a3 [o][h][w][16] -> a3t [16][6144] ----------
__global__ void k_tr_a3(const float* __restrict__ a3, float* __restrict__ a3t) {
  int k = blockIdx.x * blockDim.x + threadIdx.x;
  if (k >= 6144) return;
  const float4* s4 = reinterpret_cast<const float4*>(a3) + (size_t)k * 4;
#pragma unroll
  for (int q = 0; q < 4; ++q) {
    float4 v = s4[q];
    a3t[(size_t)(q * 4 + 0) * 6144 + k] = v.x;
    a3t[(size_t)(q * 4 + 1) * 6144 + k] = v.y;
    a3t[(size_t)(q * 4 + 2) * 6144 + k] = v.z;
    a3t[(size_t)(q * 4 + 3) * 6144 + k] = v.w;
  }
}

// ---------- FC: out[16][10178] = a3t[16][6144] . wf[10178][6144]^T + bf ------
constexpr int FC_N = 10178;
constexpr int FC_K = 6144;

// block = 256 (4 waves). Wave handles 4 consecutive n rows. Lane l covers
// k = k0 + 4l, k0 += 256. acc[j] with j = b*4 + m (b batch, m row-in-group).
// Final reduce: register transpose-reduce butterfly; lane l ends with j = l.
__global__ __launch_bounds__(256) void k_fc(const float* __restrict__ a3t,
                                            const float* __restrict__ wf,
                                            const float* __restrict__ bf,
                                            float* __restrict__ out) {
  int wv = threadIdx.x >> 6;
  int l = threadIdx.x & 63;
  int n0 = (blockIdx.x * 4 + wv) * 4;

  float acc[64];
#pragma unroll
  for (int j = 0; j < 64; ++j) acc[j] = 0.f;

  // clamp row indices for loads (store is guarded)
  int n[4];
#pragma unroll
  for (int m = 0; m < 4; ++m) {
    int nn = n0 + m;
    n[m] = nn < FC_N ? nn : FC_N - 1;
  }

  for (int k0 = 0; k0 < FC_K; k0 += 256) {
    int k = k0 + 4 * l;
    float4 xv[16];
#pragma unroll
    for (int b = 0; b < 16; ++b)
      xv[b] = *reinterpret_cast<const float4*>(a3t + (size_t)b * FC_K + k);
#pragma unroll
    for (int m = 0; m < 4; ++m) {
      float4 wv4 = *reinterpret_cast<const float4*>(wf + (size_t)n[m] * FC_K + k);
#pragma unroll
      for (int b = 0; b < 16; ++b) {
        int j = b * 4 + m;
        acc[j] = fmaf(wv4.x, xv[b].x, acc[j]);
        acc[j] = fmaf(wv4.y, xv[b].y, acc[j]);
        acc[j] = fmaf(wv4.z, xv[b].z, acc[j]);
        acc[j] = fmaf(wv4.w, xv[b].w, acc[j]);
      }
    }
  }

  // transpose-reduce: after step s, kept values' j matches lane bits 0..s.
  // Ends with acc[0] = full sum for j = l.
#pragma unroll
  for (int s = 0; s < 6; ++s) {
    int mask = 1 << s;
    int bit = (l >> s) & 1;
#pragma unroll
    for (int t = 0; t < 32; ++t) {
      if (t < (64 >> (s + 1))) {
        float e = acc[2 * t] + __shfl_xor(acc[2 * t], mask, 64);
        float o = acc[2 * t + 1] + __shfl_xor(acc[2 * t + 1], mask, 64);
        acc[t] = bit ? o : e;
      }
    }
  }

  int b = l >> 2;
  int m = l & 3;
  int nn = n0 + m;
  if (nn < FC_N) out[(size_t)b * FC_N + nn] = acc[0] + bf[nn];
}

// ---------- launch ----------
static inline int cdiv(int a, int b) { return (a + b - 1) / b; }

extern "C" void kernel_launch(void* const* d_in, const int* in_sizes, int n_in,
                              void* d_out, int out_size, void* d_ws,
                              size_t ws_size, hipStream_t stream) {
  const float* x  = (const float*)d_in[0];  // (16,3,218,178)
  const float* w1 = (const float*)d_in[1];  // (8,3,213,173,36)
  const float* b1 = (const float*)d_in[2];  // (8,213,173)
  const float* w2 = (const float*)d_in[3];  // (16,8,51,41,36)
  const float* b2 = (const float*)d_in[4];  // (16,51,41)
  const float* w3 = (const float*)d_in[5];  // (32,16,16,12,36)
  const float* b3 = (const float*)d_in[6];  // (32,16,12)
  const float* wf = (const float*)d_in[7];  // (10178,6144)
  const float* bf = (const float*)d_in[8];  // (10178,)
  float* out = (float*)d_out;               // (16,10178)

  float* ws = (float*)d_ws;
  float* xt  = ws;               // 3*218*178*16 = 1,862,592
  float* a1  = xt + 1862592;     // 8*213*173*16 = 4,716,672
  float* a1p = a1 + 4716672;     // 8*106*86*16  = 1,166,848
  float* a2  = a1p + 1166848;    // 16*51*41*16  =   535,296
  float* a3  = a2 + 535296;      // 32*16*12*16  =    98,304
  float* a3t = a3 + 98304;       // 16*6144      =    98,304

  const int B = 256;

  {  // transpose x -> xt
    int total = 3 * 218 * 178;
    k_transpose<<<cdiv(total, B), B, 0, stream>>>(x, xt, total, total);
  }
  {  // L1: stride 1, O=8, out 213x173 (16-batch threads: 294,792 positions)
    int total = 8 * 213 * 173;
    k_lc16<3, 218, 178, 213, 173, 1>
        <<<cdiv(total, B), B, 0, stream>>>(xt, w1, b1, a1, total);
  }
  {  // maxpool2 -> 106x86
    int total = 4 * 8 * 106 * 86;
    k_pool<<<cdiv(total, B), B, 0, stream>>>(a1, a1p, 213, 173, 106, 86, total);
  }
  {  // L2: stride 2, C=8 -> O=16, out 51x41 (4-batch for parallelism)
    int total = 4 * 16 * 51 * 41;
    k_lc<8, 106, 86, 51, 41, 2>
        <<<cdiv(total, B), B, 0, stream>>>(a1p, w2, b2, a2, total);
  }
  {  // L3: stride 3, C=16 -> O=32, out 16x12
    int total = 4 * 32 * 16 * 12;
    k_lc<16, 51, 41, 16, 12, 3>
        <<<cdiv(total, B), B, 0, stream>>>(a2, w3, b3, a3, total);
  }
  {  // a3 -> a3t [16][6144]
    k_tr_a3<<<cdiv(6144, B), B, 0, stream>>>(a3, a3t);
  }
  {  // FC: 637 blocks x 256; wave = 4 rows
    int grid = cdiv(FC_N, 16);
    k_fc<<<grid, B, 0, stream>>>(a3t, wf, bf, out);
  }
}

// Round 3
// 410.561 us; speedup vs baseline: 1.1102x; 1.1102x over previous
//
#include <hip/hip_runtime.h>

// ---------- helpers ----------
static __device__ __forceinline__ void fma4(float4& a, float s, float4 v) {
  a.x = fmaf(s, v.x, a.x);
  a.y = fmaf(s, v.y, a.y);
  a.z = fmaf(s, v.z, a.z);
  a.w = fmaf(s, v.w, a.w);
}
static __device__ __forceinline__ float4 relu4(float4 a) {
  return make_float4(fmaxf(a.x, 0.f), fmaxf(a.y, 0.f),
                     fmaxf(a.z, 0.f), fmaxf(a.w, 0.f));
}

// ---------- transpose x (16,C,H,W) -> xt [C][H][W][16] ----------
__global__ void k_transpose(const float* __restrict__ x, float* __restrict__ xt,
                            int chw, int total) {
  int p = blockIdx.x * blockDim.x + threadIdx.x;
  if (p >= total) return;
  float v[16];
#pragma unroll
  for (int b = 0; b < 16; ++b) v[b] = x[(size_t)b * chw + p];
  float4* o4 = reinterpret_cast<float4*>(xt) + (size_t)p * 4;
#pragma unroll
  for (int q = 0; q < 4; ++q)
    o4[q] = make_float4(v[4 * q + 0], v[4 * q + 1], v[4 * q + 2], v[4 * q + 3]);
}

// ---------- locally-connected conv, O channels x 4 batch per thread ----------
// xt  : [C][IH][IW][16], wgt: [O_tot][C][OH][OW][36], bias: [O_tot][OH][OW]
// out : [O_tot][OH][OW][16]
// thread t: bq = t&3, pos = (t>>2) % (OH*OW), ogroup = (t>>2)/(OH*OW).
// Each k4 step: batch-load 4 x float4 + O w float4 (MLP = O+4), then O*16 FMA.
template <int C, int IH, int IW, int OH, int OW, int S, int O>
__global__ void k_lc_o(const float* __restrict__ xt, const float* __restrict__ wgt,
                       const float* __restrict__ bias, float* __restrict__ out,
                       int total) {
  int t = blockIdx.x * blockDim.x + threadIdx.x;
  if (t >= total) return;
  int bq = t & 3;
  int q = t >> 2;
  int w = q % OW; q /= OW;
  int h = q % OH; q /= OH;
  int ob = q * O;  // first output channel of this thread

  float4 acc[O];
#pragma unroll
  for (int o = 0; o < O; ++o) {
    float bv = bias[((ob + o) * OH + h) * OW + w];
    acc[o] = make_float4(bv, bv, bv, bv);
  }

  const float4* x4 = reinterpret_cast<const float4*>(xt);
  const float4* w4 = reinterpret_cast<const float4*>(wgt);
  size_t hw9 = ((size_t)h * OW + w) * 9;

  for (int c = 0; c < C; ++c) {
    const float4* xc = x4 + ((size_t)(c * IH + h * S) * IW + w * S) * 4 + bq;
#pragma unroll
    for (int k4 = 0; k4 < 9; ++k4) {
      float4 xv[4];
#pragma unroll
      for (int r = 0; r < 4; ++r) {
        int k = k4 * 4 + r;
        xv[r] = xc[((k / 6) * IW + (k % 6)) * 4];
      }
      float4 wv[O];
#pragma unroll
      for (int o = 0; o < O; ++o)
        wv[o] = w4[((size_t)((ob + o) * C + c) * OH * OW) * 9 + hw9 + k4];
#pragma unroll
      for (int o = 0; o < O; ++o) {
        fma4(acc[o], wv[o].x, xv[0]);
        fma4(acc[o], wv[o].y, xv[1]);
        fma4(acc[o], wv[o].z, xv[2]);
        fma4(acc[o], wv[o].w, xv[3]);
      }
    }
  }
#pragma unroll
  for (int o = 0; o < O; ++o)
    reinterpret_cast<float4*>(out)[((size_t)((ob + o) * OH + h) * OW + w) * 4 + bq] =
        relu4(acc[o]);
}

// ---------- 2x2 maxpool on [O][IH][IW][16] -> [O][PH][PW][16] ----------
__global__ void k_pool(const float* __restrict__ in, float* __restrict__ out,
                       int IH, int IW, int PH, int PW, int total) {
  int t = blockIdx.x * blockDim.x + threadIdx.x;
  if (t >= total) return;
  int bq = t & 3;
  int p = t >> 2;
  int w = p % PW; p /= PW;
  int h = p % PH; p /= PH;
  int o = p;
  const float4* in4 = reinterpret_cast<const float4*>(in);
  size_t r0 = ((size_t)(o * IH + 2 * h) * IW + 2 * w) * 4 + bq;
  float4 a = in4[r0];
  float4 b = in4[r0 + 4];
  float4 c = in4[r0 + (size_t)IW * 4];
  float4 d = in4[r0 + (size_t)IW * 4 + 4];
  float4 m;
  m.x = fmaxf(fmaxf(a.x, b.x), fmaxf(c.x, d.x));
  m.y = fmaxf(fmaxf(a.y, b.y), fmaxf(c.y, d.y));
  m.z = fmaxf(fmaxf(a.z, b.z), fmaxf(c.z, d.z));
  m.w = fmaxf(fmaxf(a.w, b.w), fmaxf(c.w, d.w));
  reinterpret_cast<float4*>(out)[((size_t)(o * PH + h) * PW + w) * 4 + bq] = m;
}

// ---------- a3 [o][h][w][16] -> a3t [16][6144] ----------
__global__ void k_tr_a3(const float* __restrict__ a3, float* __restrict__ a3t) {
  int k = blockIdx.x * blockDim.x + threadIdx.x;
  if (k >= 6144) return;
  const float4* s4 = reinterpret_cast<const float4*>(a3) + (size_t)k * 4;
#pragma unroll
  for (int q = 0; q < 4; ++q) {
    float4 v = s4[q];
    a3t[(size_t)(q * 4 + 0) * 6144 + k] = v.x;
    a3t[(size_t)(q * 4 + 1) * 6144 + k] = v.y;
    a3t[(size_t)(q * 4 + 2) * 6144 + k] = v.z;
    a3t[(size_t)(q * 4 + 3) * 6144 + k] = v.w;
  }
}

// ---------- FC: out[16][10178] = a3t[16][6144] . wf[10178][6144]^T + bf ------
constexpr int FC_N = 10178;
constexpr int FC_K = 6144;

__global__ __launch_bounds__(256) void k_fc(const float* __restrict__ a3t,
                                            const float* __restrict__ wf,
                                            const float* __restrict__ bf,
                                            float* __restrict__ out) {
  int wv = threadIdx.x >> 6;
  int l = threadIdx.x & 63;
  int n0 = (blockIdx.x * 4 + wv) * 4;

  float acc[64];
#pragma unroll
  for (int j = 0; j < 64; ++j) acc[j] = 0.f;

  int n[4];
#pragma unroll
  for (int m = 0; m < 4; ++m) {
    int nn = n0 + m;
    n[m] = nn < FC_N ? nn : FC_N - 1;
  }

  for (int k0 = 0; k0 < FC_K; k0 += 256) {
    int k = k0 + 4 * l;
    float4 xv[16];
#pragma unroll
    for (int b = 0; b < 16; ++b)
      xv[b] = *reinterpret_cast<const float4*>(a3t + (size_t)b * FC_K + k);
#pragma unroll
    for (int m = 0; m < 4; ++m) {
      float4 wv4 = *reinterpret_cast<const float4*>(wf + (size_t)n[m] * FC_K + k);
#pragma unroll
      for (int b = 0; b < 16; ++b) {
        int j = b * 4 + m;
        acc[j] = fmaf(wv4.x, xv[b].x, acc[j]);
        acc[j] = fmaf(wv4.y, xv[b].y, acc[j]);
        acc[j] = fmaf(wv4.z, xv[b].z, acc[j]);
        acc[j] = fmaf(wv4.w, xv[b].w, acc[j]);
      }
    }
  }

#pragma unroll
  for (int s = 0; s < 6; ++s) {
    int mask = 1 << s;
    int bit = (l >> s) & 1;
#pragma unroll
    for (int t = 0; t < 32; ++t) {
      if (t < (64 >> (s + 1))) {
        float e = acc[2 * t] + __shfl_xor(acc[2 * t], mask, 64);
        float o = acc[2 * t + 1] + __shfl_xor(acc[2 * t + 1], mask, 64);
        acc[t] = bit ? o : e;
      }
    }
  }

  int b = l >> 2;
  int m = l & 3;
  int nn = n0 + m;
  if (nn < FC_N) out[(size_t)b * FC_N + nn] = acc[0] + bf[nn];
}

// ---------- launch ----------
static inline int cdiv(int a, int b) { return (a + b - 1) / b; }

extern "C" void kernel_launch(void* const* d_in, const int* in_sizes, int n_in,
                              void* d_out, int out_size, void* d_ws,
                              size_t ws_size, hipStream_t stream) {
  const float* x  = (const float*)d_in[0];  // (16,3,218,178)
  const float* w1 = (const float*)d_in[1];  // (8,3,213,173,36)
  const float* b1 = (const float*)d_in[2];  // (8,213,173)
  const float* w2 = (const float*)d_in[3];  // (16,8,51,41,36)
  const float* b2 = (const float*)d_in[4];  // (16,51,41)
  const float* w3 = (const float*)d_in[5];  // (32,16,16,12,36)
  const float* b3 = (const float*)d_in[6];  // (32,16,12)
  const float* wf = (const float*)d_in[7];  // (10178,6144)
  const float* bf = (const float*)d_in[8];  // (10178,)
  float* out = (float*)d_out;               // (16,10178)

  float* ws = (float*)d_ws;
  float* xt  = ws;               // 3*218*178*16 = 1,862,592
  float* a1  = xt + 1862592;     // 8*213*173*16 = 4,716,672
  float* a1p = a1 + 4716672;     // 8*106*86*16  = 1,166,848
  float* a2  = a1p + 1166848;    // 16*51*41*16  =   535,296
  float* a3  = a2 + 535296;      // 32*16*12*16  =    98,304
  float* a3t = a3 + 98304;       // 16*6144      =    98,304

  {  // transpose x -> xt
    int total = 3 * 218 * 178;
    k_transpose<<<cdiv(total, 256), 256, 0, stream>>>(x, xt, total, total);
  }
  {  // L1: stride 1, all 8 o per thread, 4 batch. 147,396 threads = 576 blocks
    int total = 4 * 213 * 173;
    k_lc_o<3, 218, 178, 213, 173, 1, 8>
        <<<cdiv(total, 256), 256, 0, stream>>>(xt, w1, b1, a1, total);
  }
  {  // maxpool2 -> 106x86
    int total = 4 * 8 * 106 * 86;
    k_pool<<<cdiv(total, 256), 256, 0, stream>>>(a1, a1p, 213, 173, 106, 86,
                                                 total);
  }
  {  // L2: stride 2, O=2 per thread (8 o-groups), block 128 -> 523 blocks
    int total = 4 * 51 * 41 * 8;
    k_lc_o<8, 106, 86, 51, 41, 2, 2>
        <<<cdiv(total, 128), 128, 0, stream>>>(a1p, w2, b2, a2, total);
  }
  {  // L3: stride 3, O=2 per thread (16 o-groups), block 128 -> 96 blocks
    int total = 4 * 16 * 12 * 16;
    k_lc_o<16, 51, 41, 16, 12, 3, 2>
        <<<cdiv(total, 128), 128, 0, stream>>>(a2, w3, b3, a3, total);
  }
  {  // a3 -> a3t [16][6144]
    k_tr_a3<<<cdiv(6144, 256), 256, 0, stream>>>(a3, a3t);
  }
  {  // FC
    int grid = cdiv(FC_N, 16);
    k_fc<<<grid, 256, 0, stream>>>(a3t, wf, bf, out);
  }
}

// Round 4
// 290.911 us; speedup vs baseline: 1.5668x; 1.4113x over previous
//
#include <hip/hip_runtime.h>

// ---------- helpers ----------
static __device__ __forceinline__ void fma4(float4& a, float s, float4 v) {
  a.x = fmaf(s, v.x, a.x);
  a.y = fmaf(s, v.y, a.y);
  a.z = fmaf(s, v.z, a.z);
  a.w = fmaf(s, v.w, a.w);
}
static __device__ __forceinline__ float4 relu4(float4 a) {
  return make_float4(fmaxf(a.x, 0.f), fmaxf(a.y, 0.f),
                     fmaxf(a.z, 0.f), fmaxf(a.w, 0.f));
}

// ---------- transpose x (16,C,H,W) -> xt [C][H][W][16] ----------
__global__ void k_transpose(const float* __restrict__ x, float* __restrict__ xt,
                            int chw, int total) {
  int p = blockIdx.x * blockDim.x + threadIdx.x;
  if (p >= total) return;
  float v[16];
#pragma unroll
  for (int b = 0; b < 16; ++b) v[b] = x[(size_t)b * chw + p];
  float4* o4 = reinterpret_cast<float4*>(xt) + (size_t)p * 4;
#pragma unroll
  for (int q = 0; q < 4; ++q)
    o4[q] = make_float4(v[4 * q + 0], v[4 * q + 1], v[4 * q + 2], v[4 * q + 3]);
}

// ---------- locally-connected conv (full C in-thread), O chan x 4 batch -----
// thread t: bq, (w,h), og. Used for L1 (C=3).
template <int C, int IH, int IW, int OH, int OW, int S, int O>
__global__ void k_lc_o(const float* __restrict__ xt, const float* __restrict__ wgt,
                       const float* __restrict__ bias, float* __restrict__ out,
                       int total) {
  int t = blockIdx.x * blockDim.x + threadIdx.x;
  if (t >= total) return;
  int bq = t & 3;
  int q = t >> 2;
  int w = q % OW; q /= OW;
  int h = q % OH; q /= OH;
  int ob = q * O;

  float4 acc[O];
#pragma unroll
  for (int o = 0; o < O; ++o) {
    float bv = bias[((ob + o) * OH + h) * OW + w];
    acc[o] = make_float4(bv, bv, bv, bv);
  }

  const float4* x4 = reinterpret_cast<const float4*>(xt);
  const float4* w4 = reinterpret_cast<const float4*>(wgt);
  size_t hw9 = ((size_t)h * OW + w) * 9;

  for (int c = 0; c < C; ++c) {
    const float4* xc = x4 + ((size_t)(c * IH + h * S) * IW + w * S) * 4 + bq;
#pragma unroll
    for (int k4 = 0; k4 < 9; ++k4) {
      float4 xv[4];
#pragma unroll
      for (int r = 0; r < 4; ++r) {
        int k = k4 * 4 + r;
        xv[r] = xc[((k / 6) * IW + (k % 6)) * 4];
      }
      float4 wv[O];
#pragma unroll
      for (int o = 0; o < O; ++o)
        wv[o] = w4[((size_t)((ob + o) * C + c) * OH * OW) * 9 + hw9 + k4];
#pragma unroll
      for (int o = 0; o < O; ++o) {
        fma4(acc[o], wv[o].x, xv[0]);
        fma4(acc[o], wv[o].y, xv[1]);
        fma4(acc[o], wv[o].z, xv[2]);
        fma4(acc[o], wv[o].w, xv[3]);
      }
    }
  }
#pragma unroll
  for (int o = 0; o < O; ++o)
    reinterpret_cast<float4*>(out)[((size_t)((ob + o) * OH + h) * OW + w) * 4 + bq] =
        relu4(acc[o]);
}

// ---------- lc partial: ONE input channel c per thread (C split across grid) -
// part layout: [c][O_TOT][OH][OW][16] (no bias/relu here).
template <int C_TOT, int IH, int IW, int OH, int OW, int S, int O, int OG>
__global__ void k_lc_c1(const float* __restrict__ xt, const float* __restrict__ wgt,
                        float* __restrict__ part, int total) {
  int t = blockIdx.x * blockDim.x + threadIdx.x;
  if (t >= total) return;
  int bq = t & 3;
  int q = t >> 2;
  int w = q % OW; q /= OW;
  int h = q % OH; q /= OH;
  int og = q % OG; q /= OG;
  int c = q;
  int ob = og * O;

  float4 acc[O];
#pragma unroll
  for (int o = 0; o < O; ++o) acc[o] = make_float4(0.f, 0.f, 0.f, 0.f);

  const float4* x4 = reinterpret_cast<const float4*>(xt);
  const float4* w4 = reinterpret_cast<const float4*>(wgt);
  size_t hw9 = ((size_t)h * OW + w) * 9;
  const float4* xc = x4 + ((size_t)(c * IH + h * S) * IW + w * S) * 4 + bq;

#pragma unroll
  for (int k4 = 0; k4 < 9; ++k4) {
    float4 xv[4];
#pragma unroll
    for (int r = 0; r < 4; ++r) {
      int k = k4 * 4 + r;
      xv[r] = xc[((k / 6) * IW + (k % 6)) * 4];
    }
    float4 wv[O];
#pragma unroll
    for (int o = 0; o < O; ++o)
      wv[o] = w4[((size_t)((ob + o) * C_TOT + c) * OH * OW) * 9 + hw9 + k4];
#pragma unroll
    for (int o = 0; o < O; ++o) {
      fma4(acc[o], wv[o].x, xv[0]);
      fma4(acc[o], wv[o].y, xv[1]);
      fma4(acc[o], wv[o].z, xv[2]);
      fma4(acc[o], wv[o].w, xv[3]);
    }
  }
  float4* p4 = reinterpret_cast<float4*>(part) + (size_t)c * (OG * O * OH * OW * 4);
#pragma unroll
  for (int o = 0; o < O; ++o)
    p4[((size_t)((ob + o) * OH + h) * OW + w) * 4 + bq] = acc[o];
}

// ---------- combine partials: sum CC chunks + bias + relu -------------------
// If A3T: instead of writing [pos][16] layout, scatter-write a3t[16][6144].
template <int CC, bool A3T>
__global__ void k_combine(const float* __restrict__ part,
                          const float* __restrict__ bias,
                          float* __restrict__ out, int n4total) {
  int p = blockIdx.x * blockDim.x + threadIdx.x;
  if (p >= n4total) return;
  const float4* p4 = reinterpret_cast<const float4*>(part);
  float4 acc = make_float4(0.f, 0.f, 0.f, 0.f);
#pragma unroll
  for (int c = 0; c < CC; ++c) {
    float4 v = p4[(size_t)c * n4total + p];
    acc.x += v.x; acc.y += v.y; acc.z += v.z; acc.w += v.w;
  }
  float bv = bias[p >> 2];
  acc = relu4(make_float4(acc.x + bv, acc.y + bv, acc.z + bv, acc.w + bv));
  if (A3T) {
    int k = p >> 2;   // flat (o,h,w) 0..6143
    int bq = p & 3;
    out[(size_t)(bq * 4 + 0) * 6144 + k] = acc.x;
    out[(size_t)(bq * 4 + 1) * 6144 + k] = acc.y;
    out[(size_t)(bq * 4 + 2) * 6144 + k] = acc.z;
    out[(size_t)(bq * 4 + 3) * 6144 + k] = acc.w;
  } else {
    reinterpret_cast<float4*>(out)[p] = acc;
  }
}

// ---------- 2x2 maxpool on [O][IH][IW][16] -> [O][PH][PW][16] ----------
__global__ void k_pool(const float* __restrict__ in, float* __restrict__ out,
                       int IH, int IW, int PH, int PW, int total) {
  int t = blockIdx.x * blockDim.x + threadIdx.x;
  if (t >= total) return;
  int bq = t & 3;
  int p = t >> 2;
  int w = p % PW; p /= PW;
  int h = p % PH; p /= PH;
  int o = p;
  const float4* in4 = reinterpret_cast<const float4*>(in);
  size_t r0 = ((size_t)(o * IH + 2 * h) * IW + 2 * w) * 4 + bq;
  float4 a = in4[r0];
  float4 b = in4[r0 + 4];
  float4 c = in4[r0 + (size_t)IW * 4];
  float4 d = in4[r0 + (size_t)IW * 4 + 4];
  float4 m;
  m.x = fmaxf(fmaxf(a.x, b.x), fmaxf(c.x, d.x));
  m.y = fmaxf(fmaxf(a.y, b.y), fmaxf(c.y, d.y));
  m.z = fmaxf(fmaxf(a.z, b.z), fmaxf(c.z, d.z));
  m.w = fmaxf(fmaxf(a.w, b.w), fmaxf(c.w, d.w));
  reinterpret_cast<float4*>(out)[((size_t)(o * PH + h) * PW + w) * 4 + bq] = m;
}

// ---------- FC stage 1: K split into 4 chunks of 1536 (blockIdx.y) ----------
constexpr int FC_N = 10178;
constexpr int FC_K = 6144;
constexpr int FC_KC = 4;
constexpr int FC_KLEN = FC_K / FC_KC;  // 1536

__global__ __launch_bounds__(256) void k_fc(const float* __restrict__ a3t,
                                            const float* __restrict__ wf,
                                            float* __restrict__ fcp) {
  int wv = threadIdx.x >> 6;
  int l = threadIdx.x & 63;
  int n0 = (blockIdx.x * 4 + wv) * 4;
  int kc = blockIdx.y;
  int kbase = kc * FC_KLEN;

  float acc[64];
#pragma unroll
  for (int j = 0; j < 64; ++j) acc[j] = 0.f;

  int n[4];
#pragma unroll
  for (int m = 0; m < 4; ++m) {
    int nn = n0 + m;
    n[m] = nn < FC_N ? nn : FC_N - 1;
  }

  for (int k0 = 0; k0 < FC_KLEN; k0 += 256) {
    int k = kbase + k0 + 4 * l;
    float4 xv[16];
#pragma unroll
    for (int b = 0; b < 16; ++b)
      xv[b] = *reinterpret_cast<const float4*>(a3t + (size_t)b * FC_K + k);
#pragma unroll
    for (int m = 0; m < 4; ++m) {
      float4 wv4 = *reinterpret_cast<const float4*>(wf + (size_t)n[m] * FC_K + k);
#pragma unroll
      for (int b = 0; b < 16; ++b) {
        int j = b * 4 + m;
        acc[j] = fmaf(wv4.x, xv[b].x, acc[j]);
        acc[j] = fmaf(wv4.y, xv[b].y, acc[j]);
        acc[j] = fmaf(wv4.z, xv[b].z, acc[j]);
        acc[j] = fmaf(wv4.w, xv[b].w, acc[j]);
      }
    }
  }

  // transpose-reduce butterfly: lane l ends with full sum for j = l.
#pragma unroll
  for (int s = 0; s < 6; ++s) {
    int mask = 1 << s;
    int bit = (l >> s) & 1;
#pragma unroll
    for (int t = 0; t < 32; ++t) {
      if (t < (64 >> (s + 1))) {
        float e = acc[2 * t] + __shfl_xor(acc[2 * t], mask, 64);
        float o = acc[2 * t + 1] + __shfl_xor(acc[2 * t + 1], mask, 64);
        acc[t] = bit ? o : e;
      }
    }
  }

  int b = l >> 2;
  int m = l & 3;
  int nn = n0 + m;
  if (nn < FC_N)
    fcp[((size_t)kc * 16 + b) * FC_N + nn] = acc[0];
}

// ---------- FC stage 2: sum k-chunks + bias ----------
__global__ void k_fc_comb(const float* __restrict__ fcp,
                          const float* __restrict__ bf,
                          float* __restrict__ out, int total) {
  int t = blockIdx.x * blockDim.x + threadIdx.x;
  if (t >= total) return;
  unsigned n = (unsigned)t % (unsigned)FC_N;
  float s = bf[n];
#pragma unroll
  for (int kc = 0; kc < FC_KC; ++kc) s += fcp[(size_t)kc * 16 * FC_N + t];
  out[t] = s;
}

// ---------- launch ----------
static inline int cdiv(int a, int b) { return (a + b - 1) / b; }

extern "C" void kernel_launch(void* const* d_in, const int* in_sizes, int n_in,
                              void* d_out, int out_size, void* d_ws,
                              size_t ws_size, hipStream_t stream) {
  const float* x  = (const float*)d_in[0];  // (16,3,218,178)
  const float* w1 = (const float*)d_in[1];  // (8,3,213,173,36)
  const float* b1 = (const float*)d_in[2];  // (8,213,173)
  const float* w2 = (const float*)d_in[3];  // (16,8,51,41,36)
  const float* b2 = (const float*)d_in[4];  // (16,51,41)
  const float* w3 = (const float*)d_in[5];  // (32,16,16,12,36)
  const float* b3 = (const float*)d_in[6];  // (32,16,12)
  const float* wf = (const float*)d_in[7];  // (10178,6144)
  const float* bf = (const float*)d_in[8];  // (10178,)
  float* out = (float*)d_out;               // (16,10178)

  float* ws = (float*)d_ws;
  // regions (floats); aliases are safe: stream-serialized, producer finished
  // before the aliased consumer runs.
  float* xt     = ws;                  // 1,862,592   (free after L1)
  float* a1     = ws + 1862592;        // 4,716,672   (free after pool)
  float* a1p    = ws + 6579264;        // 1,166,848   (free after L2 partials)
  float* a2     = ws + 7746112;        //   535,296
  float* a3t    = ws + 8281408;        //    98,304
  float* l2part = a1;                  // 8 * 535,296 = 4,282,368 <= a1 size
  float* l3part = xt;                  // 16 * 98,304 = 1,572,864 <= xt size
  float* fcp    = a1p;                 // 4 * 162,848 =   651,392 <= a1p size

  {  // transpose x -> xt
    int total = 3 * 218 * 178;
    k_transpose<<<cdiv(total, 256), 256, 0, stream>>>(x, xt, total, total);
  }
  {  // L1: O=2 (4 o-groups), 589,584 threads = 9 waves/SIMD
    int total = 4 * 213 * 173 * 4;
    k_lc_o<3, 218, 178, 213, 173, 1, 2>
        <<<cdiv(total, 256), 256, 0, stream>>>(xt, w1, b1, a1, total);
  }
  {  // maxpool2 -> 106x86
    int total = 4 * 8 * 106 * 86;
    k_pool<<<cdiv(total, 256), 256, 0, stream>>>(a1, a1p, 213, 173, 106, 86,
                                                 total);
  }
  {  // L2 partials: c split 8-way, O=2 (8 o-groups) -> 535,296 threads
    int total = 4 * 51 * 41 * 8 * 8;
    k_lc_c1<8, 106, 86, 51, 41, 2, 2, 8>
        <<<cdiv(total, 256), 256, 0, stream>>>(a1p, w2, l2part, total);
  }
  {  // L2 combine -> a2
    int n4 = 16 * 51 * 41 * 4;
    k_combine<8, false>
        <<<cdiv(n4, 256), 256, 0, stream>>>(l2part, b2, a2, n4);
  }
  {  // L3 partials: c split 16-way, O=1 (32 o-groups) -> 393,216 threads
    int total = 4 * 16 * 12 * 32 * 16;
    k_lc_c1<16, 51, 41, 16, 12, 3, 1, 32>
        <<<cdiv(total, 256), 256, 0, stream>>>(a2, w3, l3part, total);
  }
  {  // L3 combine -> a3t [16][6144] directly
    int n4 = 32 * 16 * 12 * 4;
    k_combine<16, true>
        <<<cdiv(n4, 256), 256, 0, stream>>>(l3part, b3, a3t, n4);
  }
  {  // FC stage 1: (637, 4) blocks -> 10,192 waves
    dim3 grid(cdiv(FC_N, 16), FC_KC);
    k_fc<<<grid, 256, 0, stream>>>(a3t, wf, fcp);
  }
  {  // FC stage 2
    int total = 16 * FC_N;
    k_fc_comb<<<cdiv(total, 256), 256, 0, stream>>>(fcp, bf, out, total);
  }
}

// Round 5
// 205.216 us; speedup vs baseline: 2.2211x; 1.4176x over previous
//
#include <hip/hip_runtime.h>

// ---------- helpers ----------
static __device__ __forceinline__ void fma4(float4& a, float s, float4 v) {
  a.x = fmaf(s, v.x, a.x);
  a.y = fmaf(s, v.y, a.y);
  a.z = fmaf(s, v.z, a.z);
  a.w = fmaf(s, v.w, a.w);
}
static __device__ __forceinline__ float4 relu4(float4 a) {
  return make_float4(fmaxf(a.x, 0.f), fmaxf(a.y, 0.f),
                     fmaxf(a.z, 0.f), fmaxf(a.w, 0.f));
}

// ---------- transpose x (16,C,H,W) -> xt [C][H][W][16] ----------
__global__ void k_transpose(const float* __restrict__ x, float* __restrict__ xt,
                            int chw, int total) {
  int p = blockIdx.x * blockDim.x + threadIdx.x;
  if (p >= total) return;
  float v[16];
#pragma unroll
  for (int b = 0; b < 16; ++b) v[b] = x[(size_t)b * chw + p];
  float4* o4 = reinterpret_cast<float4*>(xt) + (size_t)p * 4;
#pragma unroll
  for (int q = 0; q < 4; ++q)
    o4[q] = make_float4(v[4 * q + 0], v[4 * q + 1], v[4 * q + 2], v[4 * q + 3]);
}

// ---------- LDS-staged LC, c-loop inside, bias+relu fused (L1) --------------
// block = 256 (64 flat-pos x 4 bq). grid bx = tile + NT*(o_group of 4).
// LDS: wl[4o][64pos][9 float4] = 36,864 B, staged per c with coalesced loads.
template <int C, int IH, int IW, int OH, int OW, int S>
__global__ __launch_bounds__(256) void k_lc_lds_full(
    const float* __restrict__ xt, const float* __restrict__ wgt,
    const float* __restrict__ bias, float* __restrict__ out) {
  constexpr int POS = OH * OW;
  constexpr int NT = (POS + 63) / 64;
  __shared__ float4 wl[4 * 64 * 9];
  int tile = blockIdx.x % NT;
  int ob0 = (blockIdx.x / NT) * 4;
  int p0 = tile * 64;
  int PN = (POS - p0) < 64 ? (POS - p0) : 64;
  int lp = threadIdx.x >> 2, bq = threadIdx.x & 3;
  int fp = p0 + lp;
  bool act = lp < PN;
  int h = act ? fp / OW : 0;
  int w = act ? fp % OW : 0;

  float4 acc[4];
#pragma unroll
  for (int o = 0; o < 4; ++o) {
    float bv = act ? bias[(size_t)(ob0 + o) * POS + fp] : 0.f;
    acc[o] = make_float4(bv, bv, bv, bv);
  }

  const float4* x4 = reinterpret_cast<const float4*>(xt);
  const float4* w4 = reinterpret_cast<const float4*>(wgt);

  for (int c = 0; c < C; ++c) {
    __syncthreads();
    for (int i = threadIdx.x; i < 2304; i += 256) {
      int o_l = i / 576;
      int r = i % 576;
      int pos = r / 9;
      int k4 = r % 9;
      if (pos < PN)
        wl[(o_l * 64 + pos) * 9 + k4] =
            w4[((size_t)((ob0 + o_l) * C + c) * POS + p0 + pos) * 9 + k4];
    }
    __syncthreads();
    if (act) {
      const float4* xc = x4 + ((size_t)(c * IH + h * S) * IW + w * S) * 4 + bq;
#pragma unroll
      for (int k4 = 0; k4 < 9; ++k4) {
        float4 xv[4];
#pragma unroll
        for (int r = 0; r < 4; ++r) {
          int k = k4 * 4 + r;
          xv[r] = xc[((k / 6) * IW + (k % 6)) * 4];
        }
#pragma unroll
        for (int o = 0; o < 4; ++o) {
          float4 wv = wl[(o * 64 + lp) * 9 + k4];
          fma4(acc[o], wv.x, xv[0]);
          fma4(acc[o], wv.y, xv[1]);
          fma4(acc[o], wv.z, xv[2]);
          fma4(acc[o], wv.w, xv[3]);
        }
      }
    }
  }
  if (act) {
#pragma unroll
    for (int o = 0; o < 4; ++o)
      reinterpret_cast<float4*>(out)[((size_t)(ob0 + o) * POS + fp) * 4 + bq] =
          relu4(acc[o]);
  }
}

// ---------- LDS-staged LC partial: one c per block (L2/L3) ------------------
// grid bx = tile + NT*(og + OGN*c). part: [c][O_TOT*POS*16] floats, no bias.
template <int C, int IH, int IW, int OH, int OW, int S, int O_TOT>
__global__ __launch_bounds__(256) void k_lc_lds_part(
    const float* __restrict__ xt, const float* __restrict__ wgt,
    float* __restrict__ part) {
  constexpr int POS = OH * OW;
  constexpr int NT = (POS + 63) / 64;
  constexpr int OGN = O_TOT / 4;
  __shared__ float4 wl[4 * 64 * 9];
  int tile = blockIdx.x % NT;
  int rem = blockIdx.x / NT;
  int ob0 = (rem % OGN) * 4;
  int c = rem / OGN;
  int p0 = tile * 64;
  int PN = (POS - p0) < 64 ? (POS - p0) : 64;
  int lp = threadIdx.x >> 2, bq = threadIdx.x & 3;
  int fp = p0 + lp;
  bool act = lp < PN;
  int h = act ? fp / OW : 0;
  int w = act ? fp % OW : 0;

  const float4* x4 = reinterpret_cast<const float4*>(xt);
  const float4* w4 = reinterpret_cast<const float4*>(wgt);

  for (int i = threadIdx.x; i < 2304; i += 256) {
    int o_l = i / 576;
    int r = i % 576;
    int pos = r / 9;
    int k4 = r % 9;
    if (pos < PN)
      wl[(o_l * 64 + pos) * 9 + k4] =
          w4[((size_t)((ob0 + o_l) * C + c) * POS + p0 + pos) * 9 + k4];
  }
  __syncthreads();
  if (!act) return;

  float4 acc[4];
#pragma unroll
  for (int o = 0; o < 4; ++o) acc[o] = make_float4(0.f, 0.f, 0.f, 0.f);

  const float4* xc = x4 + ((size_t)(c * IH + h * S) * IW + w * S) * 4 + bq;
#pragma unroll
  for (int k4 = 0; k4 < 9; ++k4) {
    float4 xv[4];
#pragma unroll
    for (int r = 0; r < 4; ++r) {
      int k = k4 * 4 + r;
      xv[r] = xc[((k / 6) * IW + (k % 6)) * 4];
    }
#pragma unroll
    for (int o = 0; o < 4; ++o) {
      float4 wv = wl[(o * 64 + lp) * 9 + k4];
      fma4(acc[o], wv.x, xv[0]);
      fma4(acc[o], wv.y, xv[1]);
      fma4(acc[o], wv.z, xv[2]);
      fma4(acc[o], wv.w, xv[3]);
    }
  }
  float4* pp = reinterpret_cast<float4*>(part) + (size_t)c * (O_TOT * POS * 4);
#pragma unroll
  for (int o = 0; o < 4; ++o)
    pp[((size_t)(ob0 + o) * POS + fp) * 4 + bq] = acc[o];
}

// ---------- combine partials: sum CC chunks + bias + relu -------------------
template <int CC, bool A3T>
__global__ void k_combine(const float* __restrict__ part,
                          const float* __restrict__ bias,
                          float* __restrict__ out, int n4total) {
  int p = blockIdx.x * blockDim.x + threadIdx.x;
  if (p >= n4total) return;
  const float4* p4 = reinterpret_cast<const float4*>(part);
  float4 acc = make_float4(0.f, 0.f, 0.f, 0.f);
#pragma unroll
  for (int c = 0; c < CC; ++c) {
    float4 v = p4[(size_t)c * n4total + p];
    acc.x += v.x; acc.y += v.y; acc.z += v.z; acc.w += v.w;
  }
  float bv = bias[p >> 2];
  acc = relu4(make_float4(acc.x + bv, acc.y + bv, acc.z + bv, acc.w + bv));
  if (A3T) {
    int k = p >> 2;
    int bq = p & 3;
    out[(size_t)(bq * 4 + 0) * 6144 + k] = acc.x;
    out[(size_t)(bq * 4 + 1) * 6144 + k] = acc.y;
    out[(size_t)(bq * 4 + 2) * 6144 + k] = acc.z;
    out[(size_t)(bq * 4 + 3) * 6144 + k] = acc.w;
  } else {
    reinterpret_cast<float4*>(out)[p] = acc;
  }
}

// ---------- 2x2 maxpool on [O][IH][IW][16] -> [O][PH][PW][16] ----------
__global__ void k_pool(const float* __restrict__ in, float* __restrict__ out,
                       int IH, int IW, int PH, int PW, int total) {
  int t = blockIdx.x * blockDim.x + threadIdx.x;
  if (t >= total) return;
  int bq = t & 3;
  int p = t >> 2;
  int w = p % PW; p /= PW;
  int h = p % PH; p /= PH;
  int o = p;
  const float4* in4 = reinterpret_cast<const float4*>(in);
  size_t r0 = ((size_t)(o * IH + 2 * h) * IW + 2 * w) * 4 + bq;
  float4 a = in4[r0];
  float4 b = in4[r0 + 4];
  float4 c = in4[r0 + (size_t)IW * 4];
  float4 d = in4[r0 + (size_t)IW * 4 + 4];
  float4 m;
  m.x = fmaxf(fmaxf(a.x, b.x), fmaxf(c.x, d.x));
  m.y = fmaxf(fmaxf(a.y, b.y), fmaxf(c.y, d.y));
  m.z = fmaxf(fmaxf(a.z, b.z), fmaxf(c.z, d.z));
  m.w = fmaxf(fmaxf(a.w, b.w), fmaxf(c.w, d.w));
  reinterpret_cast<float4*>(out)[((size_t)(o * PH + h) * PW + w) * 4 + bq] = m;
}

// ---------- FC stage 1 ----------
// wave = 4 n-rows x 16 batch; lane l covers k = kbase+k0+4l. K split 2-way.
// xv transient (4-load groups pinned with sched_barrier) -> no AGPR shuttle.
constexpr int FC_N = 10178;
constexpr int FC_K = 6144;
constexpr int FC_KC = 2;
constexpr int FC_KLEN = FC_K / FC_KC;  // 3072

__global__ __launch_bounds__(256) void k_fc(const float* __restrict__ a3t,
                                            const float* __restrict__ wf,
                                            float* __restrict__ fcp) {
  int wv = threadIdx.x >> 6;
  int l = threadIdx.x & 63;
  int n0 = (blockIdx.x * 4 + wv) * 4;
  int kc = blockIdx.y;
  int kbase = kc * FC_KLEN;

  float acc[64];
#pragma unroll
  for (int j = 0; j < 64; ++j) acc[j] = 0.f;

  int n[4];
#pragma unroll
  for (int m = 0; m < 4; ++m) {
    int nn = n0 + m;
    n[m] = nn < FC_N ? nn : FC_N - 1;
  }

  for (int k0 = 0; k0 < FC_KLEN; k0 += 256) {
    int k = kbase + k0 + 4 * l;
    float4 wr[4];
#pragma unroll
    for (int m = 0; m < 4; ++m)
      wr[m] = *reinterpret_cast<const float4*>(wf + (size_t)n[m] * FC_K + k);
#pragma unroll
    for (int bg = 0; bg < 4; ++bg) {
      float4 xv[4];
#pragma unroll
      for (int r = 0; r < 4; ++r)
        xv[r] = *reinterpret_cast<const float4*>(a3t +
                    (size_t)(bg * 4 + r) * FC_K + k);
#pragma unroll
      for (int r = 0; r < 4; ++r) {
        int b = bg * 4 + r;
#pragma unroll
        for (int m = 0; m < 4; ++m) {
          int j = b * 4 + m;
          acc[j] = fmaf(wr[m].x, xv[r].x, acc[j]);
          acc[j] = fmaf(wr[m].y, xv[r].y, acc[j]);
          acc[j] = fmaf(wr[m].z, xv[r].z, acc[j]);
          acc[j] = fmaf(wr[m].w, xv[r].w, acc[j]);
        }
      }
      __builtin_amdgcn_sched_barrier(0);
    }
  }

  // transpose-reduce butterfly: lane l ends with full sum for j = l.
#pragma unroll
  for (int s = 0; s < 6; ++s) {
    int mask = 1 << s;
    int bit = (l >> s) & 1;
#pragma unroll
    for (int t = 0; t < 32; ++t) {
      if (t < (64 >> (s + 1))) {
        float e = acc[2 * t] + __shfl_xor(acc[2 * t], mask, 64);
        float o = acc[2 * t + 1] + __shfl_xor(acc[2 * t + 1], mask, 64);
        acc[t] = bit ? o : e;
      }
    }
  }

  int b = l >> 2;
  int m = l & 3;
  int nn = n0 + m;
  if (nn < FC_N)
    fcp[((size_t)kc * 16 + b) * FC_N + nn] = acc[0];
}

// ---------- FC stage 2: sum k-chunks + bias ----------
__global__ void k_fc_comb(const float* __restrict__ fcp,
                          const float* __restrict__ bf,
                          float* __restrict__ out, int total) {
  int t = blockIdx.x * blockDim.x + threadIdx.x;
  if (t >= total) return;
  unsigned n = (unsigned)t % (unsigned)FC_N;
  float s = bf[n];
#pragma unroll
  for (int kc = 0; kc < FC_KC; ++kc) s += fcp[(size_t)kc * 16 * FC_N + t];
  out[t] = s;
}

// ---------- launch ----------
static inline int cdiv(int a, int b) { return (a + b - 1) / b; }

extern "C" void kernel_launch(void* const* d_in, const int* in_sizes, int n_in,
                              void* d_out, int out_size, void* d_ws,
                              size_t ws_size, hipStream_t stream) {
  const float* x  = (const float*)d_in[0];  // (16,3,218,178)
  const float* w1 = (const float*)d_in[1];  // (8,3,213,173,36)
  const float* b1 = (const float*)d_in[2];  // (8,213,173)
  const float* w2 = (const float*)d_in[3];  // (16,8,51,41,36)
  const float* b2 = (const float*)d_in[4];  // (16,51,41)
  const float* w3 = (const float*)d_in[5];  // (32,16,16,12,36)
  const float* b3 = (const float*)d_in[6];  // (32,16,12)
  const float* wf = (const float*)d_in[7];  // (10178,6144)
  const float* bf = (const float*)d_in[8];  // (10178,)
  float* out = (float*)d_out;               // (16,10178)

  float* ws = (float*)d_ws;
  float* xt     = ws;                  // 1,862,592 floats (free after L1)
  float* a1     = ws + 1862592;        // 4,716,672 (free after pool)
  float* a1p    = ws + 6579264;        // 1,166,848 (free after L2 partials)
  float* a2     = ws + 7746112;        //   535,296
  float* a3t    = ws + 8281408;        //    98,304
  float* l2part = a1;                  // 8 * 535,296 = 4,282,368 <= a1
  float* l3part = xt;                  // 16 * 98,304 = 1,572,864 <= xt
  float* fcp    = a1p;                 // 2 * 162,848 =   325,696 <= a1p

  {  // transpose x -> xt
    int total = 3 * 218 * 178;
    k_transpose<<<cdiv(total, 256), 256, 0, stream>>>(x, xt, total, total);
  }
  {  // L1: POS=36849, NT=576, o-groups {0,1} -> 1152 blocks
    k_lc_lds_full<3, 218, 178, 213, 173, 1>
        <<<576 * 2, 256, 0, stream>>>(xt, w1, b1, a1);
  }
  {  // maxpool2 -> 106x86
    int total = 4 * 8 * 106 * 86;
    k_pool<<<cdiv(total, 256), 256, 0, stream>>>(a1, a1p, 213, 173, 106, 86,
                                                 total);
  }
  {  // L2 partials: POS=2091, NT=33, OGN=4, C=8 -> 1056 blocks
    k_lc_lds_part<8, 106, 86, 51, 41, 2, 16>
        <<<33 * 4 * 8, 256, 0, stream>>>(a1p, w2, l2part);
  }
  {  // L2 combine -> a2
    int n4 = 16 * 2091 * 4;
    k_combine<8, false><<<cdiv(n4, 256), 256, 0, stream>>>(l2part, b2, a2, n4);
  }
  {  // L3 partials: POS=192, NT=3, OGN=8, C=16 -> 384 blocks
    k_lc_lds_part<16, 51, 41, 16, 12, 3, 32>
        <<<3 * 8 * 16, 256, 0, stream>>>(a2, w3, l3part);
  }
  {  // L3 combine -> a3t [16][6144]
    int n4 = 32 * 192 * 4;
    k_combine<16, true><<<cdiv(n4, 256), 256, 0, stream>>>(l3part, b3, a3t, n4);
  }
  {  // FC stage 1: (637, 2) -> 5096 waves
    dim3 grid(cdiv(FC_N, 16), FC_KC);
    k_fc<<<grid, 256, 0, stream>>>(a3t, wf, fcp);
  }
  {  // FC stage 2
    int total = 16 * FC_N;
    k_fc_comb<<<cdiv(total, 256), 256, 0, stream>>>(fcp, bf, out, total);
  }
}

// Round 7
// 178.505 us; speedup vs baseline: 2.5534x; 1.1496x over previous
//
#include <hip/hip_runtime.h>

// ---------- helpers ----------
static __device__ __forceinline__ void fma4(float4& a, float s, float4 v) {
  a.x = fmaf(s, v.x, a.x);
  a.y = fmaf(s, v.y, a.y);
  a.z = fmaf(s, v.z, a.z);
  a.w = fmaf(s, v.w, a.w);
}
static __device__ __forceinline__ float4 relu4(float4 a) {
  return make_float4(fmaxf(a.x, 0.f), fmaxf(a.y, 0.f),
                     fmaxf(a.z, 0.f), fmaxf(a.w, 0.f));
}
typedef float floatv4 __attribute__((ext_vector_type(4)));
static __device__ __forceinline__ float4 ntld4(const float* p) {
  floatv4 v = __builtin_nontemporal_load(reinterpret_cast<const floatv4*>(p));
  return make_float4(v.x, v.y, v.z, v.w);
}

// ---------- transpose x (16,C,H,W) -> xt [C][H][W][16] ----------
__global__ void k_transpose(const float* __restrict__ x, float* __restrict__ xt,
                            int chw, int total) {
  int p = blockIdx.x * blockDim.x + threadIdx.x;
  if (p >= total) return;
  float v[16];
#pragma unroll
  for (int b = 0; b < 16; ++b) v[b] = x[(size_t)b * chw + p];
  float4* o4 = reinterpret_cast<float4*>(xt) + (size_t)p * 4;
#pragma unroll
  for (int q = 0; q < 4; ++q)
    o4[q] = make_float4(v[4 * q + 0], v[4 * q + 1], v[4 * q + 2], v[4 * q + 3]);
}

// ---------- LDS-staged LC, c-loop inside, bias+relu fused (L1) --------------
template <int C, int IH, int IW, int OH, int OW, int S>
__global__ __launch_bounds__(256) void k_lc_lds_full(
    const float* __restrict__ xt, const float* __restrict__ wgt,
    const float* __restrict__ bias, float* __restrict__ out) {
  constexpr int POS = OH * OW;
  constexpr int NT = (POS + 63) / 64;
  __shared__ float4 wl[4 * 64 * 9];
  int tile = blockIdx.x % NT;
  int ob0 = (blockIdx.x / NT) * 4;
  int p0 = tile * 64;
  int PN = (POS - p0) < 64 ? (POS - p0) : 64;
  int lp = threadIdx.x >> 2, bq = threadIdx.x & 3;
  int fp = p0 + lp;
  bool act = lp < PN;
  int h = act ? fp / OW : 0;
  int w = act ? fp % OW : 0;

  float4 acc[4];
#pragma unroll
  for (int o = 0; o < 4; ++o) {
    float bv = act ? bias[(size_t)(ob0 + o) * POS + fp] : 0.f;
    acc[o] = make_float4(bv, bv, bv, bv);
  }

  const float4* x4 = reinterpret_cast<const float4*>(xt);
  const float4* w4 = reinterpret_cast<const float4*>(wgt);

  for (int c = 0; c < C; ++c) {
    __syncthreads();
    for (int i = threadIdx.x; i < 2304; i += 256) {
      int o_l = i / 576;
      int r = i % 576;
      int pos = r / 9;
      int k4 = r % 9;
      if (pos < PN)
        wl[(o_l * 64 + pos) * 9 + k4] =
            w4[((size_t)((ob0 + o_l) * C + c) * POS + p0 + pos) * 9 + k4];
    }
    __syncthreads();
    if (act) {
      const float4* xc = x4 + ((size_t)(c * IH + h * S) * IW + w * S) * 4 + bq;
#pragma unroll
      for (int k4 = 0; k4 < 9; ++k4) {
        float4 xv[4];
#pragma unroll
        for (int r = 0; r < 4; ++r) {
          int k = k4 * 4 + r;
          xv[r] = xc[((k / 6) * IW + (k % 6)) * 4];
        }
#pragma unroll
        for (int o = 0; o < 4; ++o) {
          float4 wv = wl[(o * 64 + lp) * 9 + k4];
          fma4(acc[o], wv.x, xv[0]);
          fma4(acc[o], wv.y, xv[1]);
          fma4(acc[o], wv.z, xv[2]);
          fma4(acc[o], wv.w, xv[3]);
        }
      }
    }
  }
  if (act) {
#pragma unroll
    for (int o = 0; o < 4; ++o)
      reinterpret_cast<float4*>(out)[((size_t)(ob0 + o) * POS + fp) * 4 + bq] =
          relu4(acc[o]);
  }
}

// ---------- LDS-staged LC partial: one c per block (L2/L3) ------------------
template <int C, int IH, int IW, int OH, int OW, int S, int O_TOT>
__global__ __launch_bounds__(256) void k_lc_lds_part(
    const float* __restrict__ xt, const float* __restrict__ wgt,
    float* __restrict__ part) {
  constexpr int POS = OH * OW;
  constexpr int NT = (POS + 63) / 64;
  constexpr int OGN = O_TOT / 4;
  __shared__ float4 wl[4 * 64 * 9];
  int tile = blockIdx.x % NT;
  int rem = blockIdx.x / NT;
  int ob0 = (rem % OGN) * 4;
  int c = rem / OGN;
  int p0 = tile * 64;
  int PN = (POS - p0) < 64 ? (POS - p0) : 64;
  int lp = threadIdx.x >> 2, bq = threadIdx.x & 3;
  int fp = p0 + lp;
  bool act = lp < PN;
  int h = act ? fp / OW : 0;
  int w = act ? fp % OW : 0;

  const float4* x4 = reinterpret_cast<const float4*>(xt);
  const float4* w4 = reinterpret_cast<const float4*>(wgt);

  for (int i = threadIdx.x; i < 2304; i += 256) {
    int o_l = i / 576;
    int r = i % 576;
    int pos = r / 9;
    int k4 = r % 9;
    if (pos < PN)
      wl[(o_l * 64 + pos) * 9 + k4] =
          w4[((size_t)((ob0 + o_l) * C + c) * POS + p0 + pos) * 9 + k4];
  }
  __syncthreads();
  if (!act) return;

  float4 acc[4];
#pragma unroll
  for (int o = 0; o < 4; ++o) acc[o] = make_float4(0.f, 0.f, 0.f, 0.f);

  const float4* xc = x4 + ((size_t)(c * IH + h * S) * IW + w * S) * 4 + bq;
#pragma unroll
  for (int k4 = 0; k4 < 9; ++k4) {
    float4 xv[4];
#pragma unroll
    for (int r = 0; r < 4; ++r) {
      int k = k4 * 4 + r;
      xv[r] = xc[((k / 6) * IW + (k % 6)) * 4];
    }
#pragma unroll
    for (int o = 0; o < 4; ++o) {
      float4 wv = wl[(o * 64 + lp) * 9 + k4];
      fma4(acc[o], wv.x, xv[0]);
      fma4(acc[o], wv.y, xv[1]);
      fma4(acc[o], wv.z, xv[2]);
      fma4(acc[o], wv.w, xv[3]);
    }
  }
  float4* pp = reinterpret_cast<float4*>(part) + (size_t)c * (O_TOT * POS * 4);
#pragma unroll
  for (int o = 0; o < 4; ++o)
    pp[((size_t)(ob0 + o) * POS + fp) * 4 + bq] = acc[o];
}

// ---------- combine partials: sum CC chunks + bias + relu -------------------
template <int CC, bool A3T>
__global__ void k_combine(const float* __restrict__ part,
                          const float* __restrict__ bias,
                          float* __restrict__ out, int n4total) {
  int p = blockIdx.x * blockDim.x + threadIdx.x;
  if (p >= n4total) return;
  const float4* p4 = reinterpret_cast<const float4*>(part);
  float4 acc = make_float4(0.f, 0.f, 0.f, 0.f);
#pragma unroll
  for (int c = 0; c < CC; ++c) {
    float4 v = p4[(size_t)c * n4total + p];
    acc.x += v.x; acc.y += v.y; acc.z += v.z; acc.w += v.w;
  }
  float bv = bias[p >> 2];
  acc = relu4(make_float4(acc.x + bv, acc.y + bv, acc.z + bv, acc.w + bv));
  if (A3T) {
    int k = p >> 2;
    int bq = p & 3;
    out[(size_t)(bq * 4 + 0) * 6144 + k] = acc.x;
    out[(size_t)(bq * 4 + 1) * 6144 + k] = acc.y;
    out[(size_t)(bq * 4 + 2) * 6144 + k] = acc.z;
    out[(size_t)(bq * 4 + 3) * 6144 + k] = acc.w;
  } else {
    reinterpret_cast<float4*>(out)[p] = acc;
  }
}

// ---------- 2x2 maxpool on [O][IH][IW][16] -> [O][PH][PW][16] ----------
__global__ void k_pool(const float* __restrict__ in, float* __restrict__ out,
                       int IH, int IW, int PH, int PW, int total) {
  int t = blockIdx.x * blockDim.x + threadIdx.x;
  if (t >= total) return;
  int bq = t & 3;
  int p = t >> 2;
  int w = p % PW; p /= PW;
  int h = p % PH; p /= PH;
  int o = p;
  const float4* in4 = reinterpret_cast<const float4*>(in);
  size_t r0 = ((size_t)(o * IH + 2 * h) * IW + 2 * w) * 4 + bq;
  float4 a = in4[r0];
  float4 b = in4[r0 + 4];
  float4 c = in4[r0 + (size_t)IW * 4];
  float4 d = in4[r0 + (size_t)IW * 4 + 4];
  float4 m;
  m.x = fmaxf(fmaxf(a.x, b.x), fmaxf(c.x, d.x));
  m.y = fmaxf(fmaxf(a.y, b.y), fmaxf(c.y, d.y));
  m.z = fmaxf(fmaxf(a.z, b.z), fmaxf(c.z, d.z));
  m.w = fmaxf(fmaxf(a.w, b.w), fmaxf(c.w, d.w));
  reinterpret_cast<float4*>(out)[((size_t)(o * PH + h) * PW + w) * 4 + bq] = m;
}

// ---------- FC stage 1 ----------
// wave = 4 n-rows x 16 batch; lane l covers k = kbase+k0+4l. K split 2-way.
// wf rows double-buffered (wr/wrn) so HBM latency hides under the FMA ladder;
// wf loads non-temporal (single-use stream, keep a3t L2-resident).
constexpr int FC_N = 10178;
constexpr int FC_K = 6144;
constexpr int FC_KC = 2;
constexpr int FC_KLEN = FC_K / FC_KC;  // 3072

__global__ __launch_bounds__(256) void k_fc(const float* __restrict__ a3t,
                                            const float* __restrict__ wf,
                                            float* __restrict__ fcp) {
  int wv = threadIdx.x >> 6;
  int l = threadIdx.x & 63;
  int n0 = (blockIdx.x * 4 + wv) * 4;
  int kc = blockIdx.y;
  int kbase = kc * FC_KLEN;

  float acc[64];
#pragma unroll
  for (int j = 0; j < 64; ++j) acc[j] = 0.f;

  int n[4];
#pragma unroll
  for (int m = 0; m < 4; ++m) {
    int nn = n0 + m;
    n[m] = nn < FC_N ? nn : FC_N - 1;
  }

  // prologue: first wf fragment
  float4 wr[4];
  {
    int k = kbase + 4 * l;
#pragma unroll
    for (int m = 0; m < 4; ++m) wr[m] = ntld4(wf + (size_t)n[m] * FC_K + k);
  }

  for (int k0 = 0; k0 < FC_KLEN; k0 += 256) {
    int k = kbase + k0 + 4 * l;
    // prefetch next iteration's wf fragment (wraps to kbase on last iter;
    // harmless, value unused)
    int kp = (k0 + 256 < FC_KLEN) ? (k + 256) : (kbase + 4 * l);
    float4 wrn[4];
#pragma unroll
    for (int m = 0; m < 4; ++m) wrn[m] = ntld4(wf + (size_t)n[m] * FC_K + kp);

#pragma unroll
    for (int bg = 0; bg < 4; ++bg) {
      float4 xv[4];
#pragma unroll
      for (int r = 0; r < 4; ++r)
        xv[r] = *reinterpret_cast<const float4*>(a3t +
                    (size_t)(bg * 4 + r) * FC_K + k);
#pragma unroll
      for (int r = 0; r < 4; ++r) {
        int b = bg * 4 + r;
#pragma unroll
        for (int m = 0; m < 4; ++m) {
          int j = b * 4 + m;
          acc[j] = fmaf(wr[m].x, xv[r].x, acc[j]);
          acc[j] = fmaf(wr[m].y, xv[r].y, acc[j]);
          acc[j] = fmaf(wr[m].z, xv[r].z, acc[j]);
          acc[j] = fmaf(wr[m].w, xv[r].w, acc[j]);
        }
      }
      __builtin_amdgcn_sched_barrier(0);
    }
#pragma unroll
    for (int m = 0; m < 4; ++m) wr[m] = wrn[m];
  }

  // transpose-reduce butterfly: lane l ends with full sum for j = l.
#pragma unroll
  for (int s = 0; s < 6; ++s) {
    int mask = 1 << s;
    int bit = (l >> s) & 1;
#pragma unroll
    for (int t = 0; t < 32; ++t) {
      if (t < (64 >> (s + 1))) {
        float e = acc[2 * t] + __shfl_xor(acc[2 * t], mask, 64);
        float o = acc[2 * t + 1] + __shfl_xor(acc[2 * t + 1], mask, 64);
        acc[t] = bit ? o : e;
      }
    }
  }

  int b = l >> 2;
  int m = l & 3;
  int nn = n0 + m;
  if (nn < FC_N)
    fcp[((size_t)kc * 16 + b) * FC_N + nn] = acc[0];
}

// ---------- FC stage 2: sum k-chunks + bias ----------
__global__ void k_fc_comb(const float* __restrict__ fcp,
                          const float* __restrict__ bf,
                          float* __restrict__ out, int total) {
  int t = blockIdx.x * blockDim.x + threadIdx.x;
  if (t >= total) return;
  unsigned n = (unsigned)t % (unsigned)FC_N;
  float s = bf[n];
#pragma unroll
  for (int kc = 0; kc < FC_KC; ++kc) s += fcp[(size_t)kc * 16 * FC_N + t];
  out[t] = s;
}

// ---------- launch ----------
static inline int cdiv(int a, int b) { return (a + b - 1) / b; }

extern "C" void kernel_launch(void* const* d_in, const int* in_sizes, int n_in,
                              void* d_out, int out_size, void* d_ws,
                              size_t ws_size, hipStream_t stream) {
  const float* x  = (const float*)d_in[0];  // (16,3,218,178)
  const float* w1 = (const float*)d_in[1];  // (8,3,213,173,36)
  const float* b1 = (const float*)d_in[2];  // (8,213,173)
  const float* w2 = (const float*)d_in[3];  // (16,8,51,41,36)
  const float* b2 = (const float*)d_in[4];  // (16,51,41)
  const float* w3 = (const float*)d_in[5];  // (32,16,16,12,36)
  const float* b3 = (const float*)d_in[6];  // (32,16,12)
  const float* wf = (const float*)d_in[7];  // (10178,6144)
  const float* bf = (const float*)d_in[8];  // (10178,)
  float* out = (float*)d_out;               // (16,10178)

  float* ws = (float*)d_ws;
  float* xt     = ws;                  // 1,862,592 floats (free after L1)
  float* a1     = ws + 1862592;        // 4,716,672 (free after pool)
  float* a1p    = ws + 6579264;        // 1,166,848 (free after L2 partials)
  float* a2     = ws + 7746112;        //   535,296
  float* a3t    = ws + 8281408;        //    98,304
  float* l2part = a1;                  // 8 * 535,296 = 4,282,368 <= a1
  float* l3part = xt;                  // 16 * 98,304 = 1,572,864 <= xt
  float* fcp    = a1p;                 // 2 * 162,848 =   325,696 <= a1p

  {  // transpose x -> xt
    int total = 3 * 218 * 178;
    k_transpose<<<cdiv(total, 256), 256, 0, stream>>>(x, xt, total, total);
  }
  {  // L1: POS=36849, NT=576, o-groups {0,1} -> 1152 blocks
    k_lc_lds_full<3, 218, 178, 213, 173, 1>
        <<<576 * 2, 256, 0, stream>>>(xt, w1, b1, a1);
  }
  {  // maxpool2 -> 106x86
    int total = 4 * 8 * 106 * 86;
    k_pool<<<cdiv(total, 256), 256, 0, stream>>>(a1, a1p, 213, 173, 106, 86,
                                                 total);
  }
  {  // L2 partials: POS=2091, NT=33, OGN=4, C=8 -> 1056 blocks
    k_lc_lds_part<8, 106, 86, 51, 41, 2, 16>
        <<<33 * 4 * 8, 256, 0, stream>>>(a1p, w2, l2part);
  }
  {  // L2 combine -> a2
    int n4 = 16 * 2091 * 4;
    k_combine<8, false><<<cdiv(n4, 256), 256, 0, stream>>>(l2part, b2, a2, n4);
  }
  {  // L3 partials: POS=192, NT=3, OGN=8, C=16 -> 384 blocks
    k_lc_lds_part<16, 51, 41, 16, 12, 3, 32>
        <<<3 * 8 * 16, 256, 0, stream>>>(a2, w3, l3part);
  }
  {  // L3 combine -> a3t [16][6144]
    int n4 = 32 * 192 * 4;
    k_combine<16, true><<<cdiv(n4, 256), 256, 0, stream>>>(l3part, b3, a3t, n4);
  }
  {  // FC stage 1: (637, 2) -> 5096 waves
    dim3 grid(cdiv(FC_N, 16), FC_KC);
    k_fc<<<grid, 256, 0, stream>>>(a3t, wf, fcp);
  }
  {  // FC stage 2
    int total = 16 * FC_N;
    k_fc_comb<<<cdiv(total, 256), 256, 0, stream>>>(fcp, bf, out, total);
  }
}